// Round 5
// baseline (332.212 us; speedup 1.0000x reference)
//
#include <hip/hip_runtime.h>
#include <cstdint>
#include <cstddef>

#define BB 256
#define TT 128
#define AA 4
#define II 128
#define HH 256
#define K3 768  // 3*H

typedef __attribute__((ext_vector_type(8))) short short8;
typedef __attribute__((ext_vector_type(4))) float f32x4;
typedef __attribute__((ext_vector_type(4))) unsigned short ushort4_t;

// workgroup barrier that drains ONLY LDS (lgkmcnt), not vmcnt: lets HBM
// stores / L2 prefetch loads pipeline across timesteps. __syncthreads()
// would emit s_waitcnt vmcnt(0) and serialize every step on an HBM ack.
#define LGKM_BARRIER() asm volatile("s_waitcnt lgkmcnt(0)\n\ts_barrier" ::: "memory")

static __device__ __forceinline__ unsigned short f2bf(float f) {
  unsigned int b = __float_as_uint(f);
  return (unsigned short)((b + 0x7FFFu + ((b >> 16) & 1u)) >> 16);  // RNE
}
static __device__ __forceinline__ float bf2f(unsigned short u) {
  return __uint_as_float(((unsigned int)u) << 16);
}

// fp32 -> bf16 weight conversion into workspace (W_ih then W_hh, row-major kept)
__global__ void wconv_kernel(const float* __restrict__ wih,
                             const float* __restrict__ whh,
                             unsigned short* __restrict__ o) {
  int i = blockIdx.x * 512 + threadIdx.x;
  float v = (i < K3 * II) ? wih[i] : whh[i - K3 * II];
  o[i] = f2bf(v);
}

// ---------------- Phase A: gi = x * W_ih^T + b_ih (+ b_hh for r,z), bf16 ----
__global__ __launch_bounds__(512, 2) void gi_kernel(
    const float* __restrict__ x,
    const float* __restrict__ bih_g,
    const float* __restrict__ bhh_g,
    const unsigned short* __restrict__ wb,   // W_ih bf16 at ws[0]
    unsigned short* __restrict__ gi) {
  __shared__ alignas(16) unsigned short xs[64][144];
  __shared__ alignas(16) unsigned short gst[16][792];
  __shared__ float bihs[K3];

  const int tid = threadIdx.x;
  const int l = tid & 63, w = tid >> 6;
  const int c = l & 15, g = l >> 4;
  const size_t m0 = (size_t)blockIdx.x * 64;

  for (int i = tid; i < K3; i += 512)
    bihs[i] = bih_g[i] + (i < 2 * HH ? bhh_g[i] : 0.f);
  for (int i = tid; i < 64 * 128; i += 512) {
    int row = i >> 7, col = i & 127;
    xs[row][col] = f2bf(x[m0 * 128 + i]);
  }
  short8 wf[6][4];
#pragma unroll
  for (int kt = 0; kt < 6; ++kt) {
    int row = 96 * w + kt * 16 + c;
#pragma unroll
    for (int kk = 0; kk < 4; ++kk)
      wf[kt][kk] = *(const short8*)&wb[(size_t)row * II + kk * 32 + g * 8];
  }
  LGKM_BARRIER();

  for (int chunk = 0; chunk < 4; ++chunk) {
    short8 bx[4];
#pragma unroll
    for (int kk = 0; kk < 4; ++kk)
      bx[kk] = *(const short8*)&xs[chunk * 16 + c][kk * 32 + g * 8];
    f32x4 acc[6];
#pragma unroll
    for (int kt = 0; kt < 6; ++kt) acc[kt] = (f32x4){0.f, 0.f, 0.f, 0.f};
#pragma unroll
    for (int kt = 0; kt < 6; ++kt)
#pragma unroll
      for (int kk = 0; kk < 4; ++kk)
        acc[kt] = __builtin_amdgcn_mfma_f32_16x16x32_bf16(wf[kt][kk], bx[kk], acc[kt], 0, 0, 0);
#pragma unroll
    for (int kt = 0; kt < 6; ++kt) {
      int gate0 = 96 * w + kt * 16 + g * 4;
      ushort4_t p;
#pragma unroll
      for (int r = 0; r < 4; ++r) p[r] = f2bf(acc[kt][r] + bihs[gate0 + r]);
      *(ushort4_t*)&gst[c][gate0] = p;
    }
    LGKM_BARRIER();
    for (int i = tid; i < 16 * 96; i += 512) {
      int row = i / 96, seg = i - row * 96;
      *(short8*)(gi + (m0 + chunk * 16 + row) * K3 + seg * 8) =
          *(const short8*)&gst[row][seg * 8];
    }
    LGKM_BARRIER();
  }
}

// ---------------- Phase B: recurrence ----------------
// grid 256 (block = batch b), 512 thr (8 waves). Wave w owns units
// [32w,32w+32): r/z W_hh tiles in AGPRs, n tiles in LDS frag-order.
// h fp32 in owner-lane registers; h bf16 ping-pong frag-order LDS.
// t-loop unrolled x2; lgkm-only barriers (stores/loads pipeline across t);
// msk prefetched one step ahead. Transcendentals via exp2/rcp.
__global__ __launch_bounds__(512, 2) void rnn_kernel(
    const void* __restrict__ init_raw,
    const float* __restrict__ bhh_g,
    const unsigned short* __restrict__ wsb,  // ws bf16 base: [W_ih | W_hh]
    const unsigned short* __restrict__ gi,
    float* __restrict__ out) {
  extern __shared__ char smem[];
  unsigned short* wlds = (unsigned short*)smem;             // 131072 B (n-gate W)
  unsigned short* hsb = (unsigned short*)(smem + 131072);   // 2 bufs x 2048 B
  unsigned char* msk = (unsigned char*)(smem + 135168);     // 128 B
  int* detf = (int*)(smem + 135296);                        // 12 B

  const int tid = threadIdx.x;
  const int b = blockIdx.x;
  const unsigned short* whh_b = wsb + K3 * II;

  if (tid < 3) detf[tid] = 0;
  for (int i = tid; i < 2048; i += 512) *(unsigned short*)&hsb[i] = 0;
  for (int f = tid; f < 8192; f += 512) {
    int lane = f & 63, kk = (f >> 6) & 7, kt = (f >> 9) & 1, w2 = f >> 10;
    int row = 512 + w2 * 32 + kt * 16 + (lane & 15);
    int col = kk * 32 + (lane >> 4) * 8;
    *(short8*)(wlds + (size_t)f * 8) = *(const short8*)&whh_b[(size_t)row * HH + col];
  }

  // ---- is_init layout probe (verified) ----
  {
    const unsigned int* wq = (const unsigned int*)init_raw;
    int notf = 0, gt1 = 0, oddnz = 0;
    for (int i = tid; i < (BB * TT / 4); i += 512) {
      unsigned int v = wq[i];
      notf |= (v != 0u && v != 0x3F800000u);
      gt1 |= (v > 1u);
      if (i & 1) oddnz |= (v != 0u);
    }
    if (notf) atomicOr(&detf[0], 1);
    if (gt1) atomicOr(&detf[1], 1);
    if (oddnz) atomicOr(&detf[2], 1);
  }
  __syncthreads();
  if (tid < TT) {
    int layout = (!detf[0]) ? 1 : (detf[1] ? 0 : (detf[2] ? 1 : 2));
    int e = b * TT + tid;
    unsigned int v;
    if (layout == 0)      v = ((const unsigned char*)init_raw)[e];
    else if (layout == 1) v = ((const unsigned int*)init_raw)[e];
    else                  v = ((const unsigned int*)init_raw)[2 * e];
    msk[tid] = v ? 1 : 0;
  }

  const int l = tid & 63, w = tid >> 6;
  const int c = l & 15, g = l >> 4;
  const bool act = (c < AA);

  // resident W_hh tiles: r rows {32w,32w+16}, z rows {256+32w,256+32w+16}
  short8 wreg[4][8];
#pragma unroll
  for (int tile = 0; tile < 4; ++tile) {
    int row = (tile >> 1) * 256 + 32 * w + (tile & 1) * 16 + c;
#pragma unroll
    for (int kk = 0; kk < 8; ++kk)
      wreg[tile][kk] = *(const short8*)&whh_b[(size_t)row * HH + kk * 32 + g * 8];
  }
  const unsigned short* wl = wlds + w * 8192 + l * 8;

  // n-gate b_hh, hoisted to registers
  f32x4 bn[2];
#pragma unroll
  for (int k2 = 0; k2 < 2; ++k2)
#pragma unroll
    for (int r = 0; r < 4; ++r)
      bn[k2][r] = bhh_g[2 * HH + 32 * w + k2 * 16 + g * 4 + r];

  __syncthreads();

  // induction pointers (imm-offset loads/stores, one bump per t)
  const unsigned short* gp =
      gi + ((size_t)(b * TT) * AA + (c & 3)) * K3 + 32 * w + g * 4;
  float* op = out + ((size_t)(b * TT) * AA + c) * HH + 32 * w + g * 4;
  const unsigned short* hrd = hsb + ((c & 3) * 4 + g) * 8;            // read base
  unsigned short* hwr = hsb + (w * 16 + c * 4 + (g >> 1)) * 8 + (g & 1) * 4;

  f32x4 hold[2];
  hold[0] = (f32x4){0.f, 0.f, 0.f, 0.f};
  hold[1] = (f32x4){0.f, 0.f, 0.f, 0.f};

  ushort4_t gcA[6], gcB[6];
  int mA, mB;

#define GI_LOAD(GC)                               \
  do {                                            \
    GC[0] = *(const ushort4_t*)(gp);              \
    GC[1] = *(const ushort4_t*)(gp + 16);         \
    GC[2] = *(const ushort4_t*)(gp + 256);        \
    GC[3] = *(const ushort4_t*)(gp + 272);        \
    GC[4] = *(const ushort4_t*)(gp + 512);        \
    GC[5] = *(const ushort4_t*)(gp + 528);        \
    gp += AA * K3;                                \
  } while (0)

#define L2E 1.44269504088896f

#define STEP(P, GC, MK)                                                           \
  do {                                                                            \
    const bool mskt = ((MK) != 0);                                                \
    f32x4 aR[2], aZ[2], aN[2];                                                    \
    _Pragma("unroll") for (int k2 = 0; k2 < 2; ++k2) {                            \
      aR[k2] = (f32x4){0.f, 0.f, 0.f, 0.f};                                       \
      aZ[k2] = (f32x4){0.f, 0.f, 0.f, 0.f};                                       \
      aN[k2] = (f32x4){0.f, 0.f, 0.f, 0.f};                                       \
    }                                                                             \
    if (mskt) {                                                                   \
      hold[0] = (f32x4){0.f, 0.f, 0.f, 0.f};                                      \
      hold[1] = (f32x4){0.f, 0.f, 0.f, 0.f};                                      \
    } else {                                                                      \
      short8 bhf[8];                                                              \
      _Pragma("unroll") for (int kk = 0; kk < 8; ++kk)                            \
          bhf[kk] = *(const short8*)(hrd + (P) * 1024 + kk * 128);                \
      _Pragma("unroll") for (int kk = 0; kk < 8; ++kk) {                          \
        aR[0] = __builtin_amdgcn_mfma_f32_16x16x32_bf16(wreg[0][kk], bhf[kk], aR[0], 0, 0, 0); \
        aR[1] = __builtin_amdgcn_mfma_f32_16x16x32_bf16(wreg[1][kk], bhf[kk], aR[1], 0, 0, 0); \
        aZ[0] = __builtin_amdgcn_mfma_f32_16x16x32_bf16(wreg[2][kk], bhf[kk], aZ[0], 0, 0, 0); \
        aZ[1] = __builtin_amdgcn_mfma_f32_16x16x32_bf16(wreg[3][kk], bhf[kk], aZ[1], 0, 0, 0); \
        short8 an0 = *(const short8*)(wl + kk * 512);                             \
        short8 an1 = *(const short8*)(wl + 4096 + kk * 512);                      \
        aN[0] = __builtin_amdgcn_mfma_f32_16x16x32_bf16(an0, bhf[kk], aN[0], 0, 0, 0); \
        aN[1] = __builtin_amdgcn_mfma_f32_16x16x32_bf16(an1, bhf[kk], aN[1], 0, 0, 0); \
      }                                                                           \
    }                                                                             \
    if (act) {                                                                    \
      _Pragma("unroll") for (int k2 = 0; k2 < 2; ++k2) {                          \
        f32x4 hnv;                                                                \
        ushort4_t hb4;                                                            \
        _Pragma("unroll") for (int r = 0; r < 4; ++r) {                           \
          const float pr = bf2f(GC[k2][r]) + aR[k2][r];                           \
          const float pz = bf2f(GC[2 + k2][r]) + aZ[k2][r];                       \
          const float rs = __builtin_amdgcn_rcpf(1.f + __builtin_amdgcn_exp2f(-pr * L2E)); \
          const float zs = __builtin_amdgcn_rcpf(1.f + __builtin_amdgcn_exp2f(-pz * L2E)); \
          const float hn = aN[k2][r] + bn[k2][r];                                 \
          const float pre = bf2f(GC[4 + k2][r]) + rs * hn;                        \
          const float e2 = __builtin_amdgcn_exp2f(pre * (2.f * L2E));             \
          const float nn = 1.f - 2.f * __builtin_amdgcn_rcpf(1.f + e2);           \
          const float hnew = fmaf(zs, hold[k2][r] - nn, nn);                      \
          hnv[r] = hnew;                                                          \
          hb4[r] = f2bf(hnew);                                                    \
        }                                                                         \
        hold[k2] = hnv;                                                           \
        *(ushort4_t*)(hwr + (1 - (P)) * 1024 + k2 * 16) = hb4;                    \
        *(f32x4*)(op + k2 * 16) = hnv;                                            \
      }                                                                           \
    }                                                                             \
    op += AA * HH;                                                                \
  } while (0)

  GI_LOAD(gcA);  // t = 0
  mA = msk[0];
  for (int t = 0; t < TT - 2; t += 2) {
    GI_LOAD(gcB);  // t+1
    mB = msk[t + 1];
    STEP(0, gcA, mA);
    LGKM_BARRIER();
    GI_LOAD(gcA);  // t+2
    mA = msk[t + 2];
    STEP(1, gcB, mB);
    LGKM_BARRIER();
  }
  {
    GI_LOAD(gcB);  // t = 127
    mB = msk[TT - 1];
    STEP(0, gcA, mA);
    LGKM_BARRIER();
    STEP(1, gcB, mB);
  }

  if (act) {
    float* hp = out + (size_t)BB * TT * AA * HH + ((size_t)b * AA + c) * HH + 32 * w + g * 4;
    *(f32x4*)hp = hold[0];
    *(f32x4*)(hp + 16) = hold[1];
  }
#undef GI_LOAD
#undef STEP
}

// ---------------- Fallback: round-1 kernel (known-pass) ----------------
template <int WSW>
__global__ __launch_bounds__(512, 2) void gru_kernel(
    const float* __restrict__ x,
    const void* __restrict__ init_raw,
    const float* __restrict__ wih_f,
    const float* __restrict__ whh_f,
    const float* __restrict__ bih_g,
    const float* __restrict__ bhh_g,
    const unsigned short* __restrict__ wb,
    float* __restrict__ out) {
  __shared__ alignas(16) unsigned short xs[AA][II + 8];
  __shared__ alignas(16) unsigned short hsb[AA][HH + 8];
  __shared__ float hs32[AA][HH];
  __shared__ float gi_s[K3][5];
  __shared__ float gh_s[K3][5];
  __shared__ float bihs[K3];
  __shared__ float bhhs[K3];
  __shared__ unsigned char msk[TT];
  __shared__ int detf[3];

  const int tid = threadIdx.x;
  const int b = blockIdx.x;

  if (tid < 3) detf[tid] = 0;
  for (int i = tid; i < K3; i += 512) { bihs[i] = bih_g[i]; bhhs[i] = bhh_g[i]; }
  for (int i = tid; i < AA * HH; i += 512) {
    hs32[i >> 8][i & 255] = 0.f;
    hsb[i >> 8][i & 255] = 0;
  }
  __syncthreads();
  {
    const unsigned int* wq = (const unsigned int*)init_raw;
    int notf = 0, gt1 = 0, oddnz = 0;
    for (int i = tid; i < (BB * TT / 4); i += 512) {
      unsigned int v = wq[i];
      notf |= (v != 0u && v != 0x3F800000u);
      gt1 |= (v > 1u);
      if (i & 1) oddnz |= (v != 0u);
    }
    if (notf) atomicOr(&detf[0], 1);
    if (gt1) atomicOr(&detf[1], 1);
    if (oddnz) atomicOr(&detf[2], 1);
  }
  __syncthreads();
  if (tid < TT) {
    int layout = (!detf[0]) ? 1 : (detf[1] ? 0 : (detf[2] ? 1 : 2));
    int e = b * TT + tid;
    unsigned int v;
    if (layout == 0)      v = ((const unsigned char*)init_raw)[e];
    else if (layout == 1) v = ((const unsigned int*)init_raw)[e];
    else                  v = ((const unsigned int*)init_raw)[2 * e];
    msk[tid] = v ? 1 : 0;
  }
  __syncthreads();

  const int l = tid & 63;
  const int w = tid >> 6;
  const int c = l & 15;
  const int g = l >> 4;
  const bool act = (c < AA);
  const int xa = tid >> 7, xi = tid & 127;
  const float* xrow = x + (size_t)b * TT * AA * II;
  const unsigned short* wihb = wb;
  const unsigned short* whhb = wb + K3 * II;

  for (int t = 0; t < TT; ++t) {
    xs[xa][xi] = f2bf(xrow[(size_t)t * (AA * II) + tid]);
    if (msk[t]) {
      for (int i = tid; i < AA * HH; i += 512) {
        hs32[i >> 8][i & 255] = 0.f;
        hsb[i >> 8][i & 255] = 0;
      }
    }
    __syncthreads();

    short8 bx[4], bh[8];
    if (act) {
#pragma unroll
      for (int kk = 0; kk < 4; ++kk) bx[kk] = *(const short8*)&xs[c][kk * 32 + g * 8];
#pragma unroll
      for (int kk = 0; kk < 8; ++kk) bh[kk] = *(const short8*)&hsb[c][kk * 32 + g * 8];
    } else {
#pragma unroll
      for (int kk = 0; kk < 4; ++kk) bx[kk] = (short8)0;
#pragma unroll
      for (int kk = 0; kk < 8; ++kk) bh[kk] = (short8)0;
    }

#pragma unroll
    for (int kt = 0; kt < 6; ++kt) {
      const int ar = w * 96 + kt * 16 + c;
      f32x4 acc = {0.f, 0.f, 0.f, 0.f};
#pragma unroll
      for (int kk = 0; kk < 4; ++kk) {
        short8 aw;
        if (WSW) {
          aw = *(const short8*)&wihb[(size_t)ar * II + kk * 32 + g * 8];
        } else {
          const float* p = &wih_f[(size_t)ar * II + kk * 32 + g * 8];
#pragma unroll
          for (int e = 0; e < 8; ++e) aw[e] = (short)f2bf(p[e]);
        }
        acc = __builtin_amdgcn_mfma_f32_16x16x32_bf16(aw, bx[kk], acc, 0, 0, 0);
      }
      if (act) {
        const int dr = w * 96 + kt * 16 + g * 4;
#pragma unroll
        for (int r = 0; r < 4; ++r) gi_s[dr + r][c] = acc[r];
      }
    }

#pragma unroll
    for (int kt = 0; kt < 6; ++kt) {
      const int ar = w * 96 + kt * 16 + c;
      f32x4 acc = {0.f, 0.f, 0.f, 0.f};
#pragma unroll
      for (int kk = 0; kk < 8; ++kk) {
        short8 aw;
        if (WSW) {
          aw = *(const short8*)&whhb[(size_t)ar * HH + kk * 32 + g * 8];
        } else {
          const float* p = &whh_f[(size_t)ar * HH + kk * 32 + g * 8];
#pragma unroll
          for (int e = 0; e < 8; ++e) aw[e] = (short)f2bf(p[e]);
        }
        acc = __builtin_amdgcn_mfma_f32_16x16x32_bf16(aw, bh[kk], acc, 0, 0, 0);
      }
      if (act) {
        const int dr = w * 96 + kt * 16 + g * 4;
#pragma unroll
        for (int r = 0; r < 4; ++r) gh_s[dr + r][c] = acc[r];
      }
    }
    __syncthreads();

#pragma unroll
    for (int it = 0; it < 2; ++it) {
      const int idx = it * 512 + tid;
      const int a = idx >> 8, j = idx & 255;
      const float ir = gi_s[j][a] + bihs[j];
      const float iz = gi_s[HH + j][a] + bihs[HH + j];
      const float inn = gi_s[2 * HH + j][a] + bihs[2 * HH + j];
      const float hr = gh_s[j][a] + bhhs[j];
      const float hz = gh_s[HH + j][a] + bhhs[HH + j];
      const float hn = gh_s[2 * HH + j][a] + bhhs[2 * HH + j];
      const float r = 1.f / (1.f + __expf(-(ir + hr)));
      const float z = 1.f / (1.f + __expf(-(iz + hz)));
      const float pre = inn + r * hn;
      const float ea = __expf(-2.f * fabsf(pre));
      float n = (1.f - ea) / (1.f + ea);
      n = (pre < 0.f) ? -n : n;
      const float hold = hs32[a][j];
      const float hnew = (1.f - z) * n + z * hold;
      hs32[a][j] = hnew;
      hsb[a][j] = f2bf(hnew);
      out[(((size_t)b * TT + t) * AA + a) * HH + j] = hnew;
      if (t == TT - 1)
        out[(size_t)BB * TT * AA * HH + ((size_t)b * AA + a) * HH + j] = hnew;
    }
    __syncthreads();
  }
}

extern "C" void kernel_launch(void* const* d_in, const int* in_sizes, int n_in,
                              void* d_out, int out_size, void* d_ws, size_t ws_size,
                              hipStream_t stream) {
  (void)in_sizes; (void)n_in; (void)out_size;
  const float* x = (const float*)d_in[0];
  const void* is_init = d_in[1];
  const float* wih = (const float*)d_in[2];
  const float* whh = (const float*)d_in[3];
  const float* bih = (const float*)d_in[4];
  const float* bhh = (const float*)d_in[5];
  float* out = (float*)d_out;

  const size_t W_ELS = (size_t)(K3 * II + K3 * HH);        // 294,912
  const size_t W_BYTES = W_ELS * 2;                        // 589,824
  const size_t GI_BYTES = (size_t)BB * TT * AA * K3 * 2;   // 201,326,592
  const int SMEM = 135312;

  if (ws_size >= W_BYTES + GI_BYTES) {
    hipError_t e = hipFuncSetAttribute(
        (const void*)rnn_kernel, hipFuncAttributeMaxDynamicSharedMemorySize, SMEM);
    if (e == hipSuccess) {
      unsigned short* wb = (unsigned short*)d_ws;
      unsigned short* gi = wb + W_ELS;
      wconv_kernel<<<(int)(W_ELS / 512), 512, 0, stream>>>(wih, whh, wb);
      gi_kernel<<<2048, 512, 0, stream>>>(x, bih, bhh, wb, gi);
      rnn_kernel<<<BB, 512, SMEM, stream>>>(is_init, bhh, wb, gi, out);
      return;
    }
  }
  // fallback (round-1 verified path)
  if (ws_size >= W_BYTES) {
    unsigned short* wb = (unsigned short*)d_ws;
    wconv_kernel<<<(int)(W_ELS / 512), 512, 0, stream>>>(wih, whh, wb);
    gru_kernel<1><<<BB, 512, 0, stream>>>(x, is_init, wih, whh, bih, bhh, wb, out);
  } else {
    gru_kernel<0><<<BB, 512, 0, stream>>>(x, is_init, wih, whh, bih, bhh, nullptr, out);
  }
}

// Round 6
// 244.468 us; speedup vs baseline: 1.3589x; 1.3589x over previous
//
#include <hip/hip_runtime.h>
#include <cstdint>
#include <cstddef>

#define BB 256
#define TT 128
#define AA 4
#define II 128
#define HH 256
#define K3 768  // 3*H

typedef __attribute__((ext_vector_type(8))) short short8;
typedef __attribute__((ext_vector_type(4))) float f32x4;
typedef __attribute__((ext_vector_type(4))) unsigned short ushort4_t;

// workgroup barrier draining ONLY lgkmcnt (LDS), not vmcnt.
#define LGKM_BARRIER() asm volatile("s_waitcnt lgkmcnt(0)\n\ts_barrier" ::: "memory")

static __device__ __forceinline__ unsigned short f2bf(float f) {
  unsigned int b = __float_as_uint(f);
  return (unsigned short)((b + 0x7FFFu + ((b >> 16) & 1u)) >> 16);  // RNE
}
static __device__ __forceinline__ float bf2f(unsigned short u) {
  return __uint_as_float(((unsigned int)u) << 16);
}

// fp32 -> bf16 weight conversion into workspace (W_ih then W_hh, row-major kept)
__global__ void wconv_kernel(const float* __restrict__ wih,
                             const float* __restrict__ whh,
                             unsigned short* __restrict__ o) {
  int i = blockIdx.x * 512 + threadIdx.x;
  float v = (i < K3 * II) ? wih[i] : whh[i - K3 * II];
  o[i] = f2bf(v);
}

// ---------------- Phase A: gi = x * W_ih^T + b_ih (+ b_hh for r,z), bf16 ----
__global__ __launch_bounds__(512, 2) void gi_kernel(
    const float* __restrict__ x,
    const float* __restrict__ bih_g,
    const float* __restrict__ bhh_g,
    const unsigned short* __restrict__ wb,   // W_ih bf16 at ws[0]
    unsigned short* __restrict__ gi) {
  __shared__ alignas(16) unsigned short xs[64][144];
  __shared__ alignas(16) unsigned short gst[16][792];
  __shared__ float bihs[K3];

  const int tid = threadIdx.x;
  const int l = tid & 63, w = tid >> 6;
  const int c = l & 15, g = l >> 4;
  const size_t m0 = (size_t)blockIdx.x * 64;

  for (int i = tid; i < K3; i += 512)
    bihs[i] = bih_g[i] + (i < 2 * HH ? bhh_g[i] : 0.f);
  for (int i = tid; i < 64 * 128; i += 512) {
    int row = i >> 7, col = i & 127;
    xs[row][col] = f2bf(x[m0 * 128 + i]);
  }
  short8 wf[6][4];
#pragma unroll
  for (int kt = 0; kt < 6; ++kt) {
    int row = 96 * w + kt * 16 + c;
#pragma unroll
    for (int kk = 0; kk < 4; ++kk)
      wf[kt][kk] = *(const short8*)&wb[(size_t)row * II + kk * 32 + g * 8];
  }
  LGKM_BARRIER();

  for (int chunk = 0; chunk < 4; ++chunk) {
    short8 bx[4];
#pragma unroll
    for (int kk = 0; kk < 4; ++kk)
      bx[kk] = *(const short8*)&xs[chunk * 16 + c][kk * 32 + g * 8];
    f32x4 acc[6];
#pragma unroll
    for (int kt = 0; kt < 6; ++kt) acc[kt] = (f32x4){0.f, 0.f, 0.f, 0.f};
#pragma unroll
    for (int kt = 0; kt < 6; ++kt)
#pragma unroll
      for (int kk = 0; kk < 4; ++kk)
        acc[kt] = __builtin_amdgcn_mfma_f32_16x16x32_bf16(wf[kt][kk], bx[kk], acc[kt], 0, 0, 0);
#pragma unroll
    for (int kt = 0; kt < 6; ++kt) {
      int gate0 = 96 * w + kt * 16 + g * 4;
      ushort4_t p;
#pragma unroll
      for (int r = 0; r < 4; ++r) p[r] = f2bf(acc[kt][r] + bihs[gate0 + r]);
      *(ushort4_t*)&gst[c][gate0] = p;
    }
    LGKM_BARRIER();
    for (int i = tid; i < 16 * 96; i += 512) {
      int row = i / 96, seg = i - row * 96;
      *(short8*)(gi + (m0 + chunk * 16 + row) * K3 + seg * 8) =
          *(const short8*)&gst[row][seg * 8];
    }
    LGKM_BARRIER();
  }
}

// ---------------- Phase B: recurrence, spread pointwise ----------------
// grid 256 (block = batch b), 512 thr (8 waves). Wave w owns units
// [32w,32w+32): r/z W_hh tiles in regs, n tiles in LDS frag-order.
// MFMA output (16 useful lanes) is redistributed via per-wave LDS scratch
// so ALL 64 lanes run the gate pointwise (lane l -> agent g=l>>4,
// units 32w+2c,+1 with c=l&15). Quarter-rate transcendental issue drops 4x.
// h slot algebra: slot(a,j) = (j>>5)*128 + a*32 + (j&31) ushorts per buf.
__global__ __launch_bounds__(512, 2) void rnn_kernel(
    const void* __restrict__ init_raw,
    const float* __restrict__ bhh_g,
    const unsigned short* __restrict__ wsb,  // ws bf16 base: [W_ih | W_hh]
    const unsigned short* __restrict__ gi,
    float* __restrict__ out) {
  extern __shared__ char smem[];
  unsigned short* wlds = (unsigned short*)smem;             // 131072 B (n-gate W)
  unsigned short* hsb = (unsigned short*)(smem + 131072);   // 2 bufs x 2048 B
  float* scr = (float*)(smem + 135168);                     // 8 waves x 448 dwords
  unsigned char* msk = (unsigned char*)(smem + 149504);     // 128 B
  int* detf = (int*)(smem + 149632);                        // 12 B

  const int tid = threadIdx.x;
  const int b = blockIdx.x;
  const unsigned short* whh_b = wsb + K3 * II;

  if (tid < 3) detf[tid] = 0;
  for (int i = tid; i < 2048; i += 512) hsb[i] = 0;
  for (int f = tid; f < 8192; f += 512) {
    int lane = f & 63, kk = (f >> 6) & 7, kt = (f >> 9) & 1, w2 = f >> 10;
    int row = 512 + w2 * 32 + kt * 16 + (lane & 15);
    int col = kk * 32 + (lane >> 4) * 8;
    *(short8*)(wlds + (size_t)f * 8) = *(const short8*)&whh_b[(size_t)row * HH + col];
  }

  // ---- is_init layout probe (verified) ----
  {
    const unsigned int* wq = (const unsigned int*)init_raw;
    int notf = 0, gt1 = 0, oddnz = 0;
    for (int i = tid; i < (BB * TT / 4); i += 512) {
      unsigned int v = wq[i];
      notf |= (v != 0u && v != 0x3F800000u);
      gt1 |= (v > 1u);
      if (i & 1) oddnz |= (v != 0u);
    }
    if (notf) atomicOr(&detf[0], 1);
    if (gt1) atomicOr(&detf[1], 1);
    if (oddnz) atomicOr(&detf[2], 1);
  }
  __syncthreads();
  if (tid < TT) {
    int layout = (!detf[0]) ? 1 : (detf[1] ? 0 : (detf[2] ? 1 : 2));
    int e = b * TT + tid;
    unsigned int v;
    if (layout == 0)      v = ((const unsigned char*)init_raw)[e];
    else if (layout == 1) v = ((const unsigned int*)init_raw)[e];
    else                  v = ((const unsigned int*)init_raw)[2 * e];
    msk[tid] = v ? 1 : 0;
  }

  const int l = tid & 63, w = tid >> 6;
  const int c = l & 15, g = l >> 4;
  const bool act = (c < AA);

  // resident W_hh tiles: r rows {32w,32w+16}, z rows {256+32w,256+32w+16}
  short8 wreg[4][8];
#pragma unroll
  for (int tile = 0; tile < 4; ++tile) {
    int row = (tile >> 1) * 256 + 32 * w + (tile & 1) * 16 + c;
#pragma unroll
    for (int kk = 0; kk < 8; ++kk)
      wreg[tile][kk] = *(const short8*)&whh_b[(size_t)row * HH + kk * 32 + g * 8];
  }
  const unsigned short* wl = wlds + w * 8192 + l * 8;

  // spread-lane constants: agent = g, units j0 = 32w + 2c (+1)
  const int j0 = 32 * w + 2 * c;
  const float bn0 = bhh_g[2 * HH + j0];
  const float bn1 = bhh_g[2 * HH + j0 + 1];

  __syncthreads();

  // pointers
  const unsigned short* gp = gi + ((size_t)(b * TT) * AA + g) * K3 + j0;
  float* op = out + ((size_t)(b * TT) * AA + g) * HH + j0;
  const unsigned short* hrd = hsb + ((c & 3) * 4 + g) * 8;          // MFMA B-frag read
  unsigned short* hwp = hsb + w * 128 + g * 32 + 2 * c;             // spread h write
  float* swp = scr + w * 448 + (g * 4 + c) * 28;                    // scratch write (act)
  const float* srp = scr + w * 448 + (((c >> 1) & 3) * 4 + g) * 28  // scratch read
                     + (c >> 3) * 4 + 2 * (c & 1);

  float h0 = 0.f, h1 = 0.f;
  unsigned int gcA[3], gcB[3];
  int mA, mB;

#define GI_LOAD(GC)                                 \
  do {                                              \
    GC[0] = *(const unsigned int*)(gp);             \
    GC[1] = *(const unsigned int*)(gp + 256);       \
    GC[2] = *(const unsigned int*)(gp + 512);       \
    gp += AA * K3;                                  \
  } while (0)

#define L2E 1.44269504088896f

#define STEP(P, GC, MK)                                                           \
  do {                                                                           \
    const bool mskt = ((MK) != 0);                                               \
    float sR0, sR1, sZ0, sZ1, sN0, sN1;                                          \
    if (mskt) {                                                                  \
      h0 = 0.f; h1 = 0.f;                                                        \
      sR0 = sR1 = sZ0 = sZ1 = sN0 = sN1 = 0.f;                                   \
    } else {                                                                     \
      f32x4 aR[2], aZ[2], aN[2];                                                 \
      _Pragma("unroll") for (int k2 = 0; k2 < 2; ++k2) {                         \
        aR[k2] = (f32x4){0.f, 0.f, 0.f, 0.f};                                    \
        aZ[k2] = (f32x4){0.f, 0.f, 0.f, 0.f};                                    \
        aN[k2] = (f32x4){0.f, 0.f, 0.f, 0.f};                                    \
      }                                                                          \
      short8 bhf[8];                                                             \
      _Pragma("unroll") for (int kk = 0; kk < 8; ++kk)                           \
          bhf[kk] = *(const short8*)(hrd + (P) * 1024 + kk * 128);               \
      _Pragma("unroll") for (int kk = 0; kk < 8; ++kk) {                         \
        aR[0] = __builtin_amdgcn_mfma_f32_16x16x32_bf16(wreg[0][kk], bhf[kk], aR[0], 0, 0, 0); \
        aR[1] = __builtin_amdgcn_mfma_f32_16x16x32_bf16(wreg[1][kk], bhf[kk], aR[1], 0, 0, 0); \
        aZ[0] = __builtin_amdgcn_mfma_f32_16x16x32_bf16(wreg[2][kk], bhf[kk], aZ[0], 0, 0, 0); \
        aZ[1] = __builtin_amdgcn_mfma_f32_16x16x32_bf16(wreg[3][kk], bhf[kk], aZ[1], 0, 0, 0); \
        short8 an0 = *(const short8*)(wl + kk * 512);                            \
        short8 an1 = *(const short8*)(wl + 4096 + kk * 512);                     \
        aN[0] = __builtin_amdgcn_mfma_f32_16x16x32_bf16(an0, bhf[kk], aN[0], 0, 0, 0); \
        aN[1] = __builtin_amdgcn_mfma_f32_16x16x32_bf16(an1, bhf[kk], aN[1], 0, 0, 0); \
      }                                                                          \
      if (act) {                                                                 \
        *(f32x4*)(swp + 0)  = aR[0];                                             \
        *(f32x4*)(swp + 4)  = aR[1];                                             \
        *(f32x4*)(swp + 8)  = aZ[0];                                             \
        *(f32x4*)(swp + 12) = aZ[1];                                             \
        *(f32x4*)(swp + 16) = aN[0];                                             \
        *(f32x4*)(swp + 20) = aN[1];                                             \
      }                                                                          \
      float2 vR = *(const float2*)(srp);                                         \
      float2 vZ = *(const float2*)(srp + 8);                                     \
      float2 vN = *(const float2*)(srp + 16);                                    \
      sR0 = vR.x; sR1 = vR.y; sZ0 = vZ.x; sZ1 = vZ.y; sN0 = vN.x; sN1 = vN.y;    \
    }                                                                            \
    const float gr0 = bf2f((unsigned short)(GC[0]));                             \
    const float gr1 = bf2f((unsigned short)(GC[0] >> 16));                       \
    const float gz0 = bf2f((unsigned short)(GC[1]));                             \
    const float gz1 = bf2f((unsigned short)(GC[1] >> 16));                       \
    const float gn0 = bf2f((unsigned short)(GC[2]));                             \
    const float gn1 = bf2f((unsigned short)(GC[2] >> 16));                       \
    const float rs0 = __builtin_amdgcn_rcpf(1.f + __builtin_amdgcn_exp2f(-(gr0 + sR0) * L2E)); \
    const float rs1 = __builtin_amdgcn_rcpf(1.f + __builtin_amdgcn_exp2f(-(gr1 + sR1) * L2E)); \
    const float zs0 = __builtin_amdgcn_rcpf(1.f + __builtin_amdgcn_exp2f(-(gz0 + sZ0) * L2E)); \
    const float zs1 = __builtin_amdgcn_rcpf(1.f + __builtin_amdgcn_exp2f(-(gz1 + sZ1) * L2E)); \
    const float pre0 = gn0 + rs0 * (sN0 + bn0);                                  \
    const float pre1 = gn1 + rs1 * (sN1 + bn1);                                  \
    const float nn0 = 1.f - 2.f * __builtin_amdgcn_rcpf(1.f + __builtin_amdgcn_exp2f(pre0 * (2.f * L2E))); \
    const float nn1 = 1.f - 2.f * __builtin_amdgcn_rcpf(1.f + __builtin_amdgcn_exp2f(pre1 * (2.f * L2E))); \
    h0 = fmaf(zs0, h0 - nn0, nn0);                                               \
    h1 = fmaf(zs1, h1 - nn1, nn1);                                               \
    unsigned int hw = (unsigned int)f2bf(h0) | ((unsigned int)f2bf(h1) << 16);   \
    *(unsigned int*)(hwp + (1 - (P)) * 1024) = hw;                               \
    float2 o2; o2.x = h0; o2.y = h1;                                             \
    *(float2*)op = o2;                                                           \
    op += AA * HH;                                                               \
  } while (0)

  GI_LOAD(gcA);  // t = 0
  mA = msk[0];
  for (int t = 0; t < TT - 2; t += 2) {
    GI_LOAD(gcB);  // t+1
    mB = msk[t + 1];
    STEP(0, gcA, mA);
    LGKM_BARRIER();
    GI_LOAD(gcA);  // t+2
    mA = msk[t + 2];
    STEP(1, gcB, mB);
    LGKM_BARRIER();
  }
  {
    GI_LOAD(gcB);  // t = 127
    mB = msk[TT - 1];
    STEP(0, gcA, mA);
    LGKM_BARRIER();
    STEP(1, gcB, mB);
  }

  {
    float* hp = out + (size_t)BB * TT * AA * HH + ((size_t)b * AA + g) * HH + j0;
    float2 o2; o2.x = h0; o2.y = h1;
    *(float2*)hp = o2;
  }
#undef GI_LOAD
#undef STEP
}

// ---------------- Fallback: round-1 kernel (known-pass) ----------------
template <int WSW>
__global__ __launch_bounds__(512, 2) void gru_kernel(
    const float* __restrict__ x,
    const void* __restrict__ init_raw,
    const float* __restrict__ wih_f,
    const float* __restrict__ whh_f,
    const float* __restrict__ bih_g,
    const float* __restrict__ bhh_g,
    const unsigned short* __restrict__ wb,
    float* __restrict__ out) {
  __shared__ alignas(16) unsigned short xs[AA][II + 8];
  __shared__ alignas(16) unsigned short hsb[AA][HH + 8];
  __shared__ float hs32[AA][HH];
  __shared__ float gi_s[K3][5];
  __shared__ float gh_s[K3][5];
  __shared__ float bihs[K3];
  __shared__ float bhhs[K3];
  __shared__ unsigned char msk[TT];
  __shared__ int detf[3];

  const int tid = threadIdx.x;
  const int b = blockIdx.x;

  if (tid < 3) detf[tid] = 0;
  for (int i = tid; i < K3; i += 512) { bihs[i] = bih_g[i]; bhhs[i] = bhh_g[i]; }
  for (int i = tid; i < AA * HH; i += 512) {
    hs32[i >> 8][i & 255] = 0.f;
    hsb[i >> 8][i & 255] = 0;
  }
  __syncthreads();
  {
    const unsigned int* wq = (const unsigned int*)init_raw;
    int notf = 0, gt1 = 0, oddnz = 0;
    for (int i = tid; i < (BB * TT / 4); i += 512) {
      unsigned int v = wq[i];
      notf |= (v != 0u && v != 0x3F800000u);
      gt1 |= (v > 1u);
      if (i & 1) oddnz |= (v != 0u);
    }
    if (notf) atomicOr(&detf[0], 1);
    if (gt1) atomicOr(&detf[1], 1);
    if (oddnz) atomicOr(&detf[2], 1);
  }
  __syncthreads();
  if (tid < TT) {
    int layout = (!detf[0]) ? 1 : (detf[1] ? 0 : (detf[2] ? 1 : 2));
    int e = b * TT + tid;
    unsigned int v;
    if (layout == 0)      v = ((const unsigned char*)init_raw)[e];
    else if (layout == 1) v = ((const unsigned int*)init_raw)[e];
    else                  v = ((const unsigned int*)init_raw)[2 * e];
    msk[tid] = v ? 1 : 0;
  }
  __syncthreads();

  const int l = tid & 63;
  const int w = tid >> 6;
  const int c = l & 15;
  const int g = l >> 4;
  const bool act = (c < AA);
  const int xa = tid >> 7, xi = tid & 127;
  const float* xrow = x + (size_t)b * TT * AA * II;
  const unsigned short* wihb = wb;
  const unsigned short* whhb = wb + K3 * II;

  for (int t = 0; t < TT; ++t) {
    xs[xa][xi] = f2bf(xrow[(size_t)t * (AA * II) + tid]);
    if (msk[t]) {
      for (int i = tid; i < AA * HH; i += 512) {
        hs32[i >> 8][i & 255] = 0.f;
        hsb[i >> 8][i & 255] = 0;
      }
    }
    __syncthreads();

    short8 bx[4], bh[8];
    if (act) {
#pragma unroll
      for (int kk = 0; kk < 4; ++kk) bx[kk] = *(const short8*)&xs[c][kk * 32 + g * 8];
#pragma unroll
      for (int kk = 0; kk < 8; ++kk) bh[kk] = *(const short8*)&hsb[c][kk * 32 + g * 8];
    } else {
#pragma unroll
      for (int kk = 0; kk < 4; ++kk) bx[kk] = (short8)0;
#pragma unroll
      for (int kk = 0; kk < 8; ++kk) bh[kk] = (short8)0;
    }

#pragma unroll
    for (int kt = 0; kt < 6; ++kt) {
      const int ar = w * 96 + kt * 16 + c;
      f32x4 acc = {0.f, 0.f, 0.f, 0.f};
#pragma unroll
      for (int kk = 0; kk < 4; ++kk) {
        short8 aw;
        if (WSW) {
          aw = *(const short8*)&wihb[(size_t)ar * II + kk * 32 + g * 8];
        } else {
          const float* p = &wih_f[(size_t)ar * II + kk * 32 + g * 8];
#pragma unroll
          for (int e = 0; e < 8; ++e) aw[e] = (short)f2bf(p[e]);
        }
        acc = __builtin_amdgcn_mfma_f32_16x16x32_bf16(aw, bx[kk], acc, 0, 0, 0);
      }
      if (act) {
        const int dr = w * 96 + kt * 16 + g * 4;
#pragma unroll
        for (int r = 0; r < 4; ++r) gi_s[dr + r][c] = acc[r];
      }
    }

#pragma unroll
    for (int kt = 0; kt < 6; ++kt) {
      const int ar = w * 96 + kt * 16 + c;
      f32x4 acc = {0.f, 0.f, 0.f, 0.f};
#pragma unroll
      for (int kk = 0; kk < 8; ++kk) {
        short8 aw;
        if (WSW) {
          aw = *(const short8*)&whhb[(size_t)ar * HH + kk * 32 + g * 8];
        } else {
          const float* p = &whh_f[(size_t)ar * HH + kk * 32 + g * 8];
#pragma unroll
          for (int e = 0; e < 8; ++e) aw[e] = (short)f2bf(p[e]);
        }
        acc = __builtin_amdgcn_mfma_f32_16x16x32_bf16(aw, bh[kk], acc, 0, 0, 0);
      }
      if (act) {
        const int dr = w * 96 + kt * 16 + g * 4;
#pragma unroll
        for (int r = 0; r < 4; ++r) gh_s[dr + r][c] = acc[r];
      }
    }
    __syncthreads();

#pragma unroll
    for (int it = 0; it < 2; ++it) {
      const int idx = it * 512 + tid;
      const int a = idx >> 8, j = idx & 255;
      const float ir = gi_s[j][a] + bihs[j];
      const float iz = gi_s[HH + j][a] + bihs[HH + j];
      const float inn = gi_s[2 * HH + j][a] + bihs[2 * HH + j];
      const float hr = gh_s[j][a] + bhhs[j];
      const float hz = gh_s[HH + j][a] + bhhs[HH + j];
      const float hn = gh_s[2 * HH + j][a] + bhhs[2 * HH + j];
      const float r = 1.f / (1.f + __expf(-(ir + hr)));
      const float z = 1.f / (1.f + __expf(-(iz + hz)));
      const float pre = inn + r * hn;
      const float ea = __expf(-2.f * fabsf(pre));
      float n = (1.f - ea) / (1.f + ea);
      n = (pre < 0.f) ? -n : n;
      const float hold = hs32[a][j];
      const float hnew = (1.f - z) * n + z * hold;
      hs32[a][j] = hnew;
      hsb[a][j] = f2bf(hnew);
      out[(((size_t)b * TT + t) * AA + a) * HH + j] = hnew;
      if (t == TT - 1)
        out[(size_t)BB * TT * AA * HH + ((size_t)b * AA + a) * HH + j] = hnew;
    }
    __syncthreads();
  }
}

extern "C" void kernel_launch(void* const* d_in, const int* in_sizes, int n_in,
                              void* d_out, int out_size, void* d_ws, size_t ws_size,
                              hipStream_t stream) {
  (void)in_sizes; (void)n_in; (void)out_size;
  const float* x = (const float*)d_in[0];
  const void* is_init = d_in[1];
  const float* wih = (const float*)d_in[2];
  const float* whh = (const float*)d_in[3];
  const float* bih = (const float*)d_in[4];
  const float* bhh = (const float*)d_in[5];
  float* out = (float*)d_out;

  const size_t W_ELS = (size_t)(K3 * II + K3 * HH);        // 294,912
  const size_t W_BYTES = W_ELS * 2;                        // 589,824
  const size_t GI_BYTES = (size_t)BB * TT * AA * K3 * 2;   // 201,326,592
  const int SMEM = 149648;

  if (ws_size >= W_BYTES + GI_BYTES) {
    hipError_t e = hipFuncSetAttribute(
        (const void*)rnn_kernel, hipFuncAttributeMaxDynamicSharedMemorySize, SMEM);
    if (e == hipSuccess) {
      unsigned short* wb = (unsigned short*)d_ws;
      unsigned short* gi = wb + W_ELS;
      wconv_kernel<<<(int)(W_ELS / 512), 512, 0, stream>>>(wih, whh, wb);
      gi_kernel<<<2048, 512, 0, stream>>>(x, bih, bhh, wb, gi);
      rnn_kernel<<<BB, 512, SMEM, stream>>>(is_init, bhh, wb, gi, out);
      return;
    }
  }
  // fallback (round-1 verified path)
  if (ws_size >= W_BYTES) {
    unsigned short* wb = (unsigned short*)d_ws;
    wconv_kernel<<<(int)(W_ELS / 512), 512, 0, stream>>>(wih, whh, wb);
    gru_kernel<1><<<BB, 512, 0, stream>>>(x, is_init, wih, whh, bih, bhh, wb, out);
  } else {
    gru_kernel<0><<<BB, 512, 0, stream>>>(x, is_init, wih, whh, bih, bhh, nullptr, out);
  }
}